// Round 9
// baseline (486.392 us; speedup 1.0000x reference)
//
#include <hip/hip_runtime.h>

#define N_NODES 50000
#define N_EDGES 600000
#define DH 128
#define BN_EPS 1e-5f
#define SCAN_BLOCKS ((N_NODES + 255) / 256)   // 196

typedef __attribute__((ext_vector_type(8))) short bf16x8;
typedef __attribute__((ext_vector_type(4))) float f32x4;

// round-to-nearest-even fp32 -> bf16 (bit trick, sign-safe)
__device__ inline unsigned short f2bf(float x) {
  unsigned u = __float_as_uint(x);
  return (unsigned short)((u + 0x7FFFu + ((u >> 16) & 1u)) >> 16);
}
__device__ inline float bf2f(unsigned short h) {
  return __uint_as_float(((unsigned)h) << 16);
}

// async global->LDS, 16 B per lane: lane i's data lands at lds_base + i*16.
__device__ inline void gl_lds16(const unsigned short* g, unsigned short* l) {
  __builtin_amdgcn_global_load_lds(
      (const __attribute__((address_space(1))) unsigned int*)g,
      (__attribute__((address_space(3))) unsigned int*)l, 16, 0, 0);
}

// ---------------------------------------------------------------------------
// Fused weight pre-split: all 5 W matrices in ONE launch (saves 4 launches).
// Layout: MFMA B-fragment order plane[((kstep*8 + ctile)*64 + lane)*8 + j],
// k = kstep*32 + (lane>>4)*8 + j, n = ctile*16 + (lane&15). W split hi/lo
// (Wh+Wl == W to 2^-17) so GEMM error is A's bf16 rounding only.
// Blocks 0..255: head (512x128). Blocks 256+64w..: the 4 128x128 mats.
// ---------------------------------------------------------------------------
__global__ __launch_bounds__(256) void convert_W5(
    const float* __restrict__ hW, const float* __restrict__ g1,
    const float* __restrict__ l1, const float* __restrict__ g2,
    const float* __restrict__ l2,
    unsigned short* __restrict__ hH, unsigned short* __restrict__ hL,
    unsigned short* __restrict__ g1H, unsigned short* __restrict__ g1L,
    unsigned short* __restrict__ l1H, unsigned short* __restrict__ l1L,
    unsigned short* __restrict__ g2H, unsigned short* __restrict__ g2L,
    unsigned short* __restrict__ l2H, unsigned short* __restrict__ l2L) {
  int b = blockIdx.x;
  const float* W;
  unsigned short *hi, *lo;
  int idx;
  if (b < 256) {
    W = hW; hi = hH; lo = hL;
    idx = b * 256 + threadIdx.x;
  } else {
    int w = (b - 256) >> 6;
    idx = ((b - 256) & 63) * 256 + threadIdx.x;
    W = (w == 0) ? g1 : (w == 1) ? l1 : (w == 2) ? g2 : l2;
    hi = (w == 0) ? g1H : (w == 1) ? l1H : (w == 2) ? g2H : l2H;
    lo = (w == 0) ? g1L : (w == 1) ? l1L : (w == 2) ? g2L : l2L;
  }
  int k = idx >> 7;
  int n = idx & 127;
  float x = W[idx];
  unsigned short h = f2bf(x);
  unsigned short l = f2bf(x - bf2f(h));
  int kstep = k >> 5;
  int ctile = n >> 4;
  int lane = ((k >> 3) & 3) * 16 + (n & 15);
  int j = k & 7;
  size_t off = ((size_t)(kstep * 8 + ctile) * 64 + lane) * 8 + j;
  hi[off] = h;
  lo[off] = l;
}

// ---------------------------------------------------------------------------
// Coalesced fp32 -> bf16 mirror (separate pass; NEVER fuse scattered ushort
// stores into a GEMM epilogue — R4 showed 10x HBM write amplification).
// ---------------------------------------------------------------------------
__global__ __launch_bounds__(256) void to_bf16(const float* __restrict__ x,
                                               unsigned short* __restrict__ xb) {
  int i = blockIdx.x * 256 + threadIdx.x;
  if (i >= N_NODES * DH / 4) return;
  float4 v = ((const float4*)x)[i];
  ushort4 o;
  o.x = f2bf(v.x); o.y = f2bf(v.y); o.z = f2bf(v.z); o.w = f2bf(v.w);
  ((ushort4*)xb)[i] = o;
}

// ---------------------------------------------------------------------------
// Double-buffered LDS MFMA GEMM, ONE barrier per kstep.
// R8 post-mortem: single-buffer m97 shape pays full load latency per kstep
// (stage -> barrier -> compute -> barrier serializes loads against MFMA).
// Here kstep k issues A(k+1) global->reg (FIRST, so its waitcnt is vmcnt(4))
// and B(k+1) global_load_lds into buf[nxt], computes from buf[cur], converts
// and writes A(k+1) to LDS, then one __syncthreads whose vmcnt(0) drain lands
// B(k+1) — the loads get the whole compute block to fly.
// BM=64 (grid 782, 3 blocks/CU by LDS 42.25 KB), BN=128, BK=32.
// ---------------------------------------------------------------------------
template <int K, bool RELU, bool ABF16>
__global__ __launch_bounds__(256) void gemm_db(const void* __restrict__ Av,
                                               const unsigned short* __restrict__ Bh,
                                               const unsigned short* __restrict__ Bl,
                                               const float* __restrict__ bias,
                                               float* __restrict__ C, int M) {
  constexpr int KSTEPS = K / 32;
  constexpr int ASTR = 40;  // padded (2-way bank alias = free)
  __shared__ __align__(16) unsigned short Ah[2][64 * ASTR];  // 10 KB
  __shared__ __align__(16) unsigned short Bhs[2][4096];      // 16 KB
  __shared__ __align__(16) unsigned short Bls[2][4096];      // 16 KB

  const int tid = threadIdx.x;
  const int wave = tid >> 6;
  const int lane = tid & 63;
  const int m0 = blockIdx.x * 64;

  // A staging: thread owns row tid>>2 (0..63), k-oct tid&3 (8 elems)
  const int s_row = tid >> 2;
  const int s_oct = tid & 3;
  const int g_row = m0 + s_row;
  const int g_rowc = (g_row < M) ? g_row : (M - 1);
  const float* af = nullptr;
  const unsigned short* ab = nullptr;
  if (ABF16) ab = (const unsigned short*)Av + (size_t)g_rowc * K + s_oct * 8;
  else af = (const float*)Av + (size_t)g_rowc * K + s_oct * 8;

  const int rgrp = wave & 1;  // 32-row group
  const int ch = wave >> 1;   // 64-col half

  f32x4 acc[2][4];
#pragma unroll
  for (int r = 0; r < 2; ++r)
#pragma unroll
    for (int c = 0; c < 4; ++c) acc[r][c] = (f32x4){0.f, 0.f, 0.f, 0.f};

  union U8 { bf16x8 v; unsigned short u[8]; uint4 q; };

  // ---- helpers as lambdas ----
  auto issueB = [&](int ks, int buf) {
    const unsigned short* sh = Bh + (size_t)ks * 4096 + wave * 1024;
    const unsigned short* sl = Bl + (size_t)ks * 4096 + wave * 1024;
    gl_lds16(sh + lane * 8, &Bhs[buf][wave * 1024]);
    gl_lds16(sh + 512 + lane * 8, &Bhs[buf][wave * 1024 + 512]);
    gl_lds16(sl + lane * 8, &Bls[buf][wave * 1024]);
    gl_lds16(sl + 512 + lane * 8, &Bls[buf][wave * 1024 + 512]);
  };

  // ---- prologue: stage kstep 0 into buf 0 ----
  {
    U8 aw;
    if (ABF16) {
      uint4 q = *(const uint4*)(ab);           // A load issued FIRST
      issueB(0, 0);                            // then 4 gl_lds (stay in flight)
      aw.q = q;
    } else {
      float4 f0 = *(const float4*)(af);
      float4 f1 = *(const float4*)(af + 4);
      issueB(0, 0);
      aw.u[0] = f2bf(f0.x); aw.u[1] = f2bf(f0.y);
      aw.u[2] = f2bf(f0.z); aw.u[3] = f2bf(f0.w);
      aw.u[4] = f2bf(f1.x); aw.u[5] = f2bf(f1.y);
      aw.u[6] = f2bf(f1.z); aw.u[7] = f2bf(f1.w);
    }
    *(uint4*)&Ah[0][s_row * ASTR + s_oct * 8] = aw.q;
  }
  __syncthreads();  // drains gl_lds(0); buf0 complete

  for (int ks = 0; ks < KSTEPS; ++ks) {
    const int cur = ks & 1;
    const int nxt = cur ^ 1;

    // ---- issue kstep+1 loads (A global->reg first, then B gl_lds) ----
    uint4 aq;
    float4 f0, f1;
    const bool more = (ks + 1 < KSTEPS);
    if (more) {
      if (ABF16) {
        aq = *(const uint4*)(ab + (ks + 1) * 32);
      } else {
        f0 = *(const float4*)(af + (ks + 1) * 32);
        f1 = *(const float4*)(af + (ks + 1) * 32 + 4);
      }
      issueB(ks + 1, nxt);
    }

    // ---- compute from buf[cur] ----
    bf16x8 a0 = *(const bf16x8*)&Ah[cur][(rgrp * 32 + (lane & 15)) * ASTR + (lane >> 4) * 8];
    bf16x8 a1 = *(const bf16x8*)&Ah[cur][(rgrp * 32 + 16 + (lane & 15)) * ASTR + (lane >> 4) * 8];
#pragma unroll
    for (int c = 0; c < 4; ++c) {
      int ct = ch * 4 + c;
      bf16x8 bh = *(const bf16x8*)&Bhs[cur][(ct * 64 + lane) * 8];
      bf16x8 bl = *(const bf16x8*)&Bls[cur][(ct * 64 + lane) * 8];
      acc[0][c] = __builtin_amdgcn_mfma_f32_16x16x32_bf16(a0, bh, acc[0][c], 0, 0, 0);
      acc[0][c] = __builtin_amdgcn_mfma_f32_16x16x32_bf16(a0, bl, acc[0][c], 0, 0, 0);
      acc[1][c] = __builtin_amdgcn_mfma_f32_16x16x32_bf16(a1, bh, acc[1][c], 0, 0, 0);
      acc[1][c] = __builtin_amdgcn_mfma_f32_16x16x32_bf16(a1, bl, acc[1][c], 0, 0, 0);
    }

    // ---- convert + write A(k+1) to buf[nxt] (waits A regs: vmcnt(4)) ----
    if (more) {
      U8 aw;
      if (ABF16) {
        aw.q = aq;
      } else {
        aw.u[0] = f2bf(f0.x); aw.u[1] = f2bf(f0.y);
        aw.u[2] = f2bf(f0.z); aw.u[3] = f2bf(f0.w);
        aw.u[4] = f2bf(f1.x); aw.u[5] = f2bf(f1.y);
        aw.u[6] = f2bf(f1.z); aw.u[7] = f2bf(f1.w);
      }
      *(uint4*)&Ah[nxt][s_row * ASTR + s_oct * 8] = aw.q;
    }
    __syncthreads();  // drains B(k+1) gl_lds; buf[nxt] complete
  }

  // ---- epilogue: C/D layout col=lane&15, row=(lane>>4)*4+reg ----
  const int coln = lane & 15;
  const int rown = (lane >> 4) * 4;
#pragma unroll
  for (int c = 0; c < 4; ++c) {
    int colg = (ch * 4 + c) * 16 + coln;
    float bv = bias[colg];
#pragma unroll
    for (int r = 0; r < 2; ++r) {
#pragma unroll
      for (int reg = 0; reg < 4; ++reg) {
        int row = m0 + rgrp * 32 + r * 16 + rown + reg;
        if (row < M) {
          float v = acc[r][c][reg] + bv;
          if (RELU) v = fmaxf(v, 0.f);
          C[(size_t)row * DH + colg] = v;
        }
      }
    }
  }
}

// ---------------------------------------------------------------------------
// CSR build: degree histogram -> exclusive scan (3 kernels) -> cursor fill.
// ---------------------------------------------------------------------------
__global__ __launch_bounds__(256) void count_deg(const int* __restrict__ eidx,
                                                 int* __restrict__ cnt) {
  int e = blockIdx.x * 256 + threadIdx.x;
  if (e < N_EDGES) atomicAdd(&cnt[eidx[N_EDGES + e]], 1);
}

__global__ __launch_bounds__(256) void scan_block(const int* __restrict__ cnt,
                                                  int* __restrict__ rs,
                                                  int* __restrict__ partials) {
  int t = threadIdx.x;
  int i = blockIdx.x * 256 + t;
  int v = (i < N_NODES) ? cnt[i] : 0;
  __shared__ int s[256];
  s[t] = v;
  __syncthreads();
#pragma unroll
  for (int off = 1; off < 256; off <<= 1) {
    int add = (t >= off) ? s[t - off] : 0;
    __syncthreads();
    s[t] += add;
    __syncthreads();
  }
  if (i < N_NODES) rs[i] = s[t] - v;
  if (t == 255) partials[blockIdx.x] = s[255];
}

__global__ __launch_bounds__(256) void scan_partials(int* __restrict__ partials) {
  int t = threadIdx.x;
  int v = (t < SCAN_BLOCKS) ? partials[t] : 0;
  __shared__ int s[256];
  s[t] = v;
  __syncthreads();
#pragma unroll
  for (int off = 1; off < 256; off <<= 1) {
    int add = (t >= off) ? s[t - off] : 0;
    __syncthreads();
    s[t] += add;
    __syncthreads();
  }
  if (t < SCAN_BLOCKS) partials[t] = s[t] - v;
}

__global__ __launch_bounds__(256) void add_offsets(int* __restrict__ rs,
                                                   const int* __restrict__ partials) {
  int i = blockIdx.x * 256 + threadIdx.x;
  if (i < N_NODES) rs[i] += partials[blockIdx.x];
  if (i == 0) rs[N_NODES] = N_EDGES;
}

__global__ __launch_bounds__(256) void fill_csr(const int* __restrict__ eidx,
                                                const int* __restrict__ rs,
                                                int* __restrict__ cursor,
                                                int* __restrict__ esrc) {
  int e = blockIdx.x * 256 + threadIdx.x;
  if (e >= N_EDGES) return;
  int d = eidx[N_EDGES + e];
  int p = atomicAdd(&cursor[d], 1);
  esrc[rs[d] + p] = eidx[e];
}

// ---------------------------------------------------------------------------
// Aggregation gather (bf16 neighbors): yb[i] = bf16(x[i] + sum_j xb[src_j]).
// Wave per node; lane handles dims (2*lane, 2*lane+1) via one uint load/edge.
// ---------------------------------------------------------------------------
__global__ __launch_bounds__(256) void gin_aggregate_bf16(
    const unsigned short* __restrict__ xb, const float* __restrict__ x,
    const int* __restrict__ rs, const int* __restrict__ esrc,
    unsigned* __restrict__ yb) {
  int node = blockIdx.x * 4 + (threadIdx.x >> 6);
  int lane = threadIdx.x & 63;
  if (node >= N_NODES) return;
  float2 acc = ((const float2*)x)[(size_t)node * 64 + lane];
  const unsigned* xb2 = (const unsigned*)xb;  // 2 bf16 per uint
  int beg = rs[node];
  int end = rs[node + 1];
  int j = beg;
  for (; j + 4 <= end; j += 4) {
    int s0 = esrc[j + 0];
    int s1 = esrc[j + 1];
    int s2 = esrc[j + 2];
    int s3 = esrc[j + 3];
    unsigned v0 = xb2[(size_t)s0 * 64 + lane];
    unsigned v1 = xb2[(size_t)s1 * 64 + lane];
    unsigned v2 = xb2[(size_t)s2 * 64 + lane];
    unsigned v3 = xb2[(size_t)s3 * 64 + lane];
    acc.x += (__uint_as_float(v0 << 16) + __uint_as_float(v1 << 16)) +
             (__uint_as_float(v2 << 16) + __uint_as_float(v3 << 16));
    acc.y += (__uint_as_float(v0 & 0xFFFF0000u) + __uint_as_float(v1 & 0xFFFF0000u)) +
             (__uint_as_float(v2 & 0xFFFF0000u) + __uint_as_float(v3 & 0xFFFF0000u));
  }
  for (; j < end; ++j) {
    unsigned v = xb2[(size_t)esrc[j] * 64 + lane];
    acc.x += __uint_as_float(v << 16);
    acc.y += __uint_as_float(v & 0xFFFF0000u);
  }
  yb[(size_t)node * 64 + lane] =
      (unsigned)f2bf(acc.x) | ((unsigned)f2bf(acc.y) << 16);
}

// ---------------------------------------------------------------------------
// Tail: z[i] = dot(x[i,:], tail_W) + tail_b, plus BN batch-stat partials.
// ---------------------------------------------------------------------------
__global__ __launch_bounds__(256) void tail_bn1(const float* __restrict__ x,
                                                const float* __restrict__ tw,
                                                const float* __restrict__ tb,
                                                float* __restrict__ z,
                                                float* __restrict__ red) {
  const int lane = threadIdx.x & 31;
  const int grp = threadIdx.x >> 5;
  float4 w = *(const float4*)(tw + lane * 4);
  float accS = 0.f, accQ = 0.f;
  for (int node = blockIdx.x * 8 + grp; node < N_NODES; node += gridDim.x * 8) {
    float4 v = *(const float4*)(x + (size_t)node * DH + lane * 4);
    float p = v.x * w.x + v.y * w.y + v.z * w.z + v.w * w.w;
#pragma unroll
    for (int m = 16; m; m >>= 1) p += __shfl_xor(p, m, 32);
    if (lane == 0) {
      float zv = p + tb[0];
      z[node] = zv;
      accS += zv;
      accQ += zv * zv;
    }
  }
  __shared__ float sS[256];
  __shared__ float sQ[256];
  sS[threadIdx.x] = accS;
  sQ[threadIdx.x] = accQ;
  __syncthreads();
  for (int s = 128; s; s >>= 1) {
    if (threadIdx.x < s) {
      sS[threadIdx.x] += sS[threadIdx.x + s];
      sQ[threadIdx.x] += sQ[threadIdx.x + s];
    }
    __syncthreads();
  }
  if (threadIdx.x == 0) {
    atomicAdd(&red[0], sS[0]);
    atomicAdd(&red[1], sQ[0]);
  }
}

__global__ __launch_bounds__(256) void bn2(const float* __restrict__ z,
                                           const float* __restrict__ red,
                                           const float* __restrict__ gamma,
                                           const float* __restrict__ beta,
                                           float* __restrict__ out) {
  int i = blockIdx.x * 256 + threadIdx.x;
  if (i >= N_NODES) return;
  float mu = red[0] * (1.0f / N_NODES);
  float var = red[1] * (1.0f / N_NODES) - mu * mu;
  out[i] = (z[i] - mu) * rsqrtf(var + BN_EPS) * gamma[0] + beta[0];
}

// ---------------------------------------------------------------------------
extern "C" void kernel_launch(void* const* d_in, const int* in_sizes, int n_in,
                              void* d_out, int out_size, void* d_ws, size_t ws_size,
                              hipStream_t stream) {
  const float* feature = (const float*)d_in[0];
  const int* eidx = (const int*)d_in[1];
  const float* head_W = (const float*)d_in[2];
  const float* head_b = (const float*)d_in[3];
  const float* gin_W1 = (const float*)d_in[4];
  const float* gin_b1 = (const float*)d_in[5];
  const float* lin_W1 = (const float*)d_in[6];
  const float* lin_b1 = (const float*)d_in[7];
  const float* gin_W2 = (const float*)d_in[8];
  const float* gin_b2 = (const float*)d_in[9];
  const float* lin_W2 = (const float*)d_in[10];
  const float* lin_b2 = (const float*)d_in[11];
  const float* tail_W = (const float*)d_in[12];
  const float* tail_b = (const float*)d_in[13];
  const float* bn_gamma = (const float*)d_in[14];
  const float* bn_beta = (const float*)d_in[15];

  float* X = (float*)d_ws;                       // N x 128 fp32
  float* H = X + (size_t)N_NODES * DH;           // N x 128 fp32
  float* z = H + (size_t)N_NODES * DH;           // N
  float* red = z + N_NODES;                      // 2 floats
  int* row_start = (int*)(red + 2);              // N+1
  int* cnt = row_start + (N_NODES + 1);          // N
  int* partials = cnt + N_NODES;                 // 256
  int* esrc = partials + 256;                    // E
  unsigned short* wp =
      (unsigned short*)(((uintptr_t)(esrc + N_EDGES) + 15) & ~(uintptr_t)15);
  unsigned short* hH = wp;            // head hi: 512*128
  unsigned short* hL = hH + 65536;    // head lo
  unsigned short* g1H = hL + 65536;   // 128*128 each below
  unsigned short* g1L = g1H + 16384;
  unsigned short* l1H = g1L + 16384;
  unsigned short* l1L = l1H + 16384;
  unsigned short* g2H = l1L + 16384;
  unsigned short* g2L = g2H + 16384;
  unsigned short* l2H = g2L + 16384;
  unsigned short* l2L = l2H + 16384;
  unsigned short* xb = l2L + 16384;              // bf16 mirror, N x 128
  unsigned* yb = (unsigned*)(xb + (size_t)N_NODES * DH);  // agg out bf16 N x 128

  const int gemm_grid = (N_NODES + 63) / 64;     // 782
  const int edge_grid = (N_EDGES + 255) / 256;
  const int agg_grid = (N_NODES + 3) / 4;
  const int cvt_grid = (N_NODES * DH / 4 + 255) / 256;

  // ---- weight pre-split: one fused launch ----
  convert_W5<<<512, 256, 0, stream>>>(head_W, gin_W1, lin_W1, gin_W2, lin_W2,
                                      hH, hL, g1H, g1L, l1H, l1L, g2H, g2L,
                                      l2H, l2L);

  // ---- CSR build (once; reused by both GIN layers) ----
  hipMemsetAsync(cnt, 0, N_NODES * sizeof(int), stream);
  hipMemsetAsync(red, 0, 2 * sizeof(float), stream);
  count_deg<<<edge_grid, 256, 0, stream>>>(eidx, cnt);
  scan_block<<<SCAN_BLOCKS, 256, 0, stream>>>(cnt, row_start, partials);
  scan_partials<<<1, 256, 0, stream>>>(partials);
  add_offsets<<<SCAN_BLOCKS, 256, 0, stream>>>(row_start, partials);
  hipMemsetAsync(cnt, 0, N_NODES * sizeof(int), stream);
  fill_csr<<<edge_grid, 256, 0, stream>>>(eidx, row_start, cnt, esrc);

  // ---- head: X = relu(feature @ head_W + head_b) ----
  gemm_db<512, true, false><<<gemm_grid, 256, 0, stream>>>(
      feature, hH, hL, head_b, X, N_NODES);

  // ---- layer 1 ----
  to_bf16<<<cvt_grid, 256, 0, stream>>>(X, xb);
  gin_aggregate_bf16<<<agg_grid, 256, 0, stream>>>(xb, X, row_start, esrc, yb);
  gemm_db<128, true, true><<<gemm_grid, 256, 0, stream>>>(
      yb, g1H, g1L, gin_b1, H, N_NODES);
  gemm_db<128, false, false><<<gemm_grid, 256, 0, stream>>>(
      H, l1H, l1L, lin_b1, X, N_NODES);

  // ---- layer 2 ----
  to_bf16<<<cvt_grid, 256, 0, stream>>>(X, xb);
  gin_aggregate_bf16<<<agg_grid, 256, 0, stream>>>(xb, X, row_start, esrc, yb);
  gemm_db<128, true, true><<<gemm_grid, 256, 0, stream>>>(
      yb, g2H, g2L, gin_b2, H, N_NODES);
  gemm_db<128, false, false><<<gemm_grid, 256, 0, stream>>>(
      H, l2H, l2L, lin_b2, X, N_NODES);

  // ---- tail + batchnorm ----
  tail_bn1<<<256, 256, 0, stream>>>(X, tail_W, tail_b, z, red);
  bn2<<<(N_NODES + 255) / 256, 256, 0, stream>>>(z, red, bn_gamma, bn_beta, (float*)d_out);
}

// Round 10
// 425.942 us; speedup vs baseline: 1.1419x; 1.1419x over previous
//
#include <hip/hip_runtime.h>

#define N_NODES 50000
#define N_EDGES 600000
#define DH 128
#define BN_EPS 1e-5f
#define SCAN_BLOCKS ((N_NODES + 255) / 256)   // 196

typedef __attribute__((ext_vector_type(8))) short bf16x8;
typedef __attribute__((ext_vector_type(4))) float f32x4;

// round-to-nearest-even fp32 -> bf16 (bit trick, sign-safe)
__device__ inline unsigned short f2bf(float x) {
  unsigned u = __float_as_uint(x);
  return (unsigned short)((u + 0x7FFFu + ((u >> 16) & 1u)) >> 16);
}
__device__ inline float bf2f(unsigned short h) {
  return __uint_as_float(((unsigned)h) << 16);
}

// async global->LDS, 16 B per lane: lane i's data lands at lds_base + i*16.
__device__ inline void gl_lds16(const unsigned short* g, unsigned short* l) {
  __builtin_amdgcn_global_load_lds(
      (const __attribute__((address_space(1))) unsigned int*)g,
      (__attribute__((address_space(3))) unsigned int*)l, 16, 0, 0);
}

// ---------------------------------------------------------------------------
// Fused weight pre-split (one launch): MFMA B-fragment order
// plane[((kstep32*8 + ctile)*64 + lane)*8 + j], k = kstep32*32 + (lane>>4)*8+j,
// n = ctile*16 + (lane&15). W split hi/lo (Wh+Wl == W to 2^-17) so GEMM error
// is A's bf16 rounding only.
// ---------------------------------------------------------------------------
__global__ __launch_bounds__(256) void convert_W5(
    const float* __restrict__ hW, const float* __restrict__ g1,
    const float* __restrict__ l1, const float* __restrict__ g2,
    const float* __restrict__ l2,
    unsigned short* __restrict__ hH, unsigned short* __restrict__ hL,
    unsigned short* __restrict__ g1H, unsigned short* __restrict__ g1L,
    unsigned short* __restrict__ l1H, unsigned short* __restrict__ l1L,
    unsigned short* __restrict__ g2H, unsigned short* __restrict__ g2L,
    unsigned short* __restrict__ l2H, unsigned short* __restrict__ l2L) {
  int b = blockIdx.x;
  const float* W;
  unsigned short *hi, *lo;
  int idx;
  if (b < 256) {
    W = hW; hi = hH; lo = hL;
    idx = b * 256 + threadIdx.x;
  } else {
    int w = (b - 256) >> 6;
    idx = ((b - 256) & 63) * 256 + threadIdx.x;
    W = (w == 0) ? g1 : (w == 1) ? l1 : (w == 2) ? g2 : l2;
    hi = (w == 0) ? g1H : (w == 1) ? l1H : (w == 2) ? g2H : l2H;
    lo = (w == 0) ? g1L : (w == 1) ? l1L : (w == 2) ? g2L : l2L;
  }
  int k = idx >> 7;
  int n = idx & 127;
  float x = W[idx];
  unsigned short h = f2bf(x);
  unsigned short l = f2bf(x - bf2f(h));
  int kstep = k >> 5;
  int ctile = n >> 4;
  int lane = ((k >> 3) & 3) * 16 + (n & 15);
  int j = k & 7;
  size_t off = ((size_t)(kstep * 8 + ctile) * 64 + lane) * 8 + j;
  hi[off] = h;
  lo[off] = l;
}

// ---------------------------------------------------------------------------
// Coalesced fp32 -> bf16 mirror (separate pass; NEVER fuse scattered ushort
// stores into a GEMM epilogue — R4 showed 10x HBM write amplification).
// ---------------------------------------------------------------------------
__global__ __launch_bounds__(256) void to_bf16(const float* __restrict__ x,
                                               unsigned short* __restrict__ xb) {
  int i = blockIdx.x * 256 + threadIdx.x;
  if (i >= N_NODES * DH / 4) return;
  float4 v = ((const float4*)x)[i];
  ushort4 o;
  o.x = f2bf(v.x); o.y = f2bf(v.y); o.z = f2bf(v.z); o.w = f2bf(v.w);
  ((ushort4*)xb)[i] = o;
}

// ---------------------------------------------------------------------------
// Head GEMM (K=512), R8 single-buffer 2-barrier structure but BK=64:
// halves the number of barrier-drain events (8 ksteps instead of 16).
// BM=64, BN=128, 4 waves; wave = 32 rows x 64 cols; 32 MFMA + 20 ds_read
// per kstep. LDS ~41 KB -> 3 blocks/CU at grid 782 (occupancy preserved).
// ---------------------------------------------------------------------------
__global__ __launch_bounds__(256) void gemm_head(const float* __restrict__ A,
                                                 const unsigned short* __restrict__ Bh,
                                                 const unsigned short* __restrict__ Bl,
                                                 const float* __restrict__ bias,
                                                 float* __restrict__ C, int M) {
  constexpr int K = 512;
  constexpr int KSTEPS = K / 64;
  constexpr int ASTR = 72;  // 64 k + 8 pad (2-way bank alias = free)
  __shared__ __align__(16) unsigned short Ah[64 * ASTR];   // 9.2 KB
  __shared__ __align__(16) unsigned short Bhs[2][4096];    // 16 KB
  __shared__ __align__(16) unsigned short Bls[2][4096];    // 16 KB

  const int tid = threadIdx.x;
  const int wave = tid >> 6;
  const int lane = tid & 63;
  const int m0 = blockIdx.x * 64;

  // A staging: thread owns row tid>>2 (0..63), 16-elem group tid&3
  const int s_row = tid >> 2;
  const int s_grp = tid & 3;
  const int g_row = m0 + s_row;
  const int g_rowc = (g_row < M) ? g_row : (M - 1);
  const float* af = A + (size_t)g_rowc * K + s_grp * 16;

  const int rgrp = wave & 1;  // 32-row group
  const int ch = wave >> 1;   // 64-col half

  f32x4 acc[2][4];
#pragma unroll
  for (int r = 0; r < 2; ++r)
#pragma unroll
    for (int c = 0; c < 4; ++c) acc[r][c] = (f32x4){0.f, 0.f, 0.f, 0.f};

  for (int ks = 0; ks < KSTEPS; ++ks) {
    // ---- stage A (64 rows x 64 k fp32 -> bf16) ----
    {
      float4 f0 = *(const float4*)(af + ks * 64);
      float4 f1 = *(const float4*)(af + ks * 64 + 4);
      float4 f2 = *(const float4*)(af + ks * 64 + 8);
      float4 f3 = *(const float4*)(af + ks * 64 + 12);
      ushort4 h0, h1, h2, h3;
      h0.x = f2bf(f0.x); h0.y = f2bf(f0.y); h0.z = f2bf(f0.z); h0.w = f2bf(f0.w);
      h1.x = f2bf(f1.x); h1.y = f2bf(f1.y); h1.z = f2bf(f1.z); h1.w = f2bf(f1.w);
      h2.x = f2bf(f2.x); h2.y = f2bf(f2.y); h2.z = f2bf(f2.z); h2.w = f2bf(f2.w);
      h3.x = f2bf(f3.x); h3.y = f2bf(f3.y); h3.z = f2bf(f3.z); h3.w = f2bf(f3.w);
      int base = s_row * ASTR + s_grp * 16;
      *(ushort4*)&Ah[base + 0] = h0;
      *(ushort4*)&Ah[base + 4] = h1;
      *(ushort4*)&Ah[base + 8] = h2;
      *(ushort4*)&Ah[base + 12] = h3;
    }
    // ---- stage B: two 32-k sub-steps, 8 KB per plane each ----
#pragma unroll
    for (int s = 0; s < 2; ++s) {
      const unsigned short* sh = Bh + (size_t)(2 * ks + s) * 4096 + wave * 1024;
      const unsigned short* sl = Bl + (size_t)(2 * ks + s) * 4096 + wave * 1024;
      gl_lds16(sh + lane * 8, &Bhs[s][wave * 1024]);
      gl_lds16(sh + 512 + lane * 8, &Bhs[s][wave * 1024 + 512]);
      gl_lds16(sl + lane * 8, &Bls[s][wave * 1024]);
      gl_lds16(sl + 512 + lane * 8, &Bls[s][wave * 1024 + 512]);
    }
    __syncthreads();

    // ---- compute: 2 k-chunks x 4 c-tiles x (hi+lo) x 2 row-frags ----
#pragma unroll
    for (int s = 0; s < 2; ++s) {
      bf16x8 a0 = *(const bf16x8*)&Ah[(rgrp * 32 + (lane & 15)) * ASTR + s * 32 + (lane >> 4) * 8];
      bf16x8 a1 = *(const bf16x8*)&Ah[(rgrp * 32 + 16 + (lane & 15)) * ASTR + s * 32 + (lane >> 4) * 8];
#pragma unroll
      for (int c = 0; c < 4; ++c) {
        int ct = ch * 4 + c;
        bf16x8 bh = *(const bf16x8*)&Bhs[s][(ct * 64 + lane) * 8];
        bf16x8 bl = *(const bf16x8*)&Bls[s][(ct * 64 + lane) * 8];
        acc[0][c] = __builtin_amdgcn_mfma_f32_16x16x32_bf16(a0, bh, acc[0][c], 0, 0, 0);
        acc[0][c] = __builtin_amdgcn_mfma_f32_16x16x32_bf16(a0, bl, acc[0][c], 0, 0, 0);
        acc[1][c] = __builtin_amdgcn_mfma_f32_16x16x32_bf16(a1, bh, acc[1][c], 0, 0, 0);
        acc[1][c] = __builtin_amdgcn_mfma_f32_16x16x32_bf16(a1, bl, acc[1][c], 0, 0, 0);
      }
    }
    __syncthreads();
  }

  // ---- epilogue: C/D layout col=lane&15, row=(lane>>4)*4+reg; relu ----
  const int coln = lane & 15;
  const int rown = (lane >> 4) * 4;
#pragma unroll
  for (int c = 0; c < 4; ++c) {
    int colg = (ch * 4 + c) * 16 + coln;
    float bv = bias[colg];
#pragma unroll
    for (int r = 0; r < 2; ++r) {
#pragma unroll
      for (int reg = 0; reg < 4; ++reg) {
        int row = m0 + rgrp * 32 + r * 16 + rown + reg;
        if (row < M) {
          float v = fmaxf(acc[r][c][reg] + bv, 0.f);
          C[(size_t)row * DH + colg] = v;
        }
      }
    }
  }
}

// ---------------------------------------------------------------------------
// Fused GIN MLP pair: X = (relu(y @ W1 + b1)) @ W2 + b2, one kernel.
// Stage 1 (4 ksteps, BK=32, R8 structure): A = yb (bf16), B = W1 planes.
// h = relu(acc+b1) -> LDS bf16 buffer (same rounding point as the old
// H-roundtrip -> identical numerics). Stage 2: A-frags ds_read from h,
// B = W2 planes. Eliminates H (50 MB HBM), one launch, zero stage-2 A-fetch.
// LDS: 5 + 16 + 17.4 = 38.4 KB -> 3 blocks/CU at grid 782.
// ---------------------------------------------------------------------------
__global__ __launch_bounds__(256) void gemm_gin(
    const unsigned short* __restrict__ yb,
    const unsigned short* __restrict__ B1h, const unsigned short* __restrict__ B1l,
    const float* __restrict__ b1,
    const unsigned short* __restrict__ B2h, const unsigned short* __restrict__ B2l,
    const float* __restrict__ b2, float* __restrict__ X, int M) {
  constexpr int K = 128;
  constexpr int KSTEPS = K / 32;
  constexpr int ASTR = 40;
  constexpr int HSTR = 136;  // 128 + 8 pad
  __shared__ __align__(16) unsigned short Ah[64 * ASTR];   // 5 KB
  __shared__ __align__(16) unsigned short Bhs[4096];       // 8 KB
  __shared__ __align__(16) unsigned short Bls[4096];       // 8 KB
  __shared__ __align__(16) unsigned short Hb[64 * HSTR];   // 17.4 KB

  const int tid = threadIdx.x;
  const int wave = tid >> 6;
  const int lane = tid & 63;
  const int m0 = blockIdx.x * 64;

  const int s_row = tid >> 2;
  const int s_oct = tid & 3;
  const int g_row = m0 + s_row;
  const int g_rowc = (g_row < M) ? g_row : (M - 1);
  const unsigned short* ab = yb + (size_t)g_rowc * K + s_oct * 8;

  const int rgrp = wave & 1;
  const int ch = wave >> 1;
  const int coln = lane & 15;
  const int rown = (lane >> 4) * 4;

  auto issueB = [&](const unsigned short* Bh, const unsigned short* Bl, int ks) {
    const unsigned short* sh = Bh + (size_t)ks * 4096 + wave * 1024;
    const unsigned short* sl = Bl + (size_t)ks * 4096 + wave * 1024;
    gl_lds16(sh + lane * 8, &Bhs[wave * 1024]);
    gl_lds16(sh + 512 + lane * 8, &Bhs[wave * 1024 + 512]);
    gl_lds16(sl + lane * 8, &Bls[wave * 1024]);
    gl_lds16(sl + 512 + lane * 8, &Bls[wave * 1024 + 512]);
  };

  f32x4 acc[2][4];
#pragma unroll
  for (int r = 0; r < 2; ++r)
#pragma unroll
    for (int c = 0; c < 4; ++c) acc[r][c] = (f32x4){0.f, 0.f, 0.f, 0.f};

  // ================= stage 1: h = relu(y @ W1 + b1) =================
  for (int ks = 0; ks < KSTEPS; ++ks) {
    *(uint4*)&Ah[s_row * ASTR + s_oct * 8] = *(const uint4*)(ab + ks * 32);
    issueB(B1h, B1l, ks);
    __syncthreads();
    bf16x8 a0 = *(const bf16x8*)&Ah[(rgrp * 32 + (lane & 15)) * ASTR + (lane >> 4) * 8];
    bf16x8 a1 = *(const bf16x8*)&Ah[(rgrp * 32 + 16 + (lane & 15)) * ASTR + (lane >> 4) * 8];
#pragma unroll
    for (int c = 0; c < 4; ++c) {
      int ct = ch * 4 + c;
      bf16x8 bh = *(const bf16x8*)&Bhs[(ct * 64 + lane) * 8];
      bf16x8 bl = *(const bf16x8*)&Bls[(ct * 64 + lane) * 8];
      acc[0][c] = __builtin_amdgcn_mfma_f32_16x16x32_bf16(a0, bh, acc[0][c], 0, 0, 0);
      acc[0][c] = __builtin_amdgcn_mfma_f32_16x16x32_bf16(a0, bl, acc[0][c], 0, 0, 0);
      acc[1][c] = __builtin_amdgcn_mfma_f32_16x16x32_bf16(a1, bh, acc[1][c], 0, 0, 0);
      acc[1][c] = __builtin_amdgcn_mfma_f32_16x16x32_bf16(a1, bl, acc[1][c], 0, 0, 0);
    }
    __syncthreads();
  }

  // ---- h -> LDS bf16 (local rows, C/D layout scatter; LDS scatter is cheap) ----
#pragma unroll
  for (int c = 0; c < 4; ++c) {
    int colg = (ch * 4 + c) * 16 + coln;
    float bv = b1[colg];
#pragma unroll
    for (int r = 0; r < 2; ++r) {
#pragma unroll
      for (int reg = 0; reg < 4; ++reg) {
        int lrow = rgrp * 32 + r * 16 + rown + reg;
        float v = fmaxf(acc[r][c][reg] + bv, 0.f);
        Hb[lrow * HSTR + colg] = f2bf(v);
      }
      // reset acc for stage 2
      acc[r][c] = (f32x4){0.f, 0.f, 0.f, 0.f};
    }
  }

  // ================= stage 2: X = h @ W2 + b2 =================
  for (int ks = 0; ks < KSTEPS; ++ks) {
    issueB(B2h, B2l, ks);
    __syncthreads();  // first iter: also publishes Hb to all waves
    bf16x8 a0 = *(const bf16x8*)&Hb[(rgrp * 32 + (lane & 15)) * HSTR + ks * 32 + (lane >> 4) * 8];
    bf16x8 a1 = *(const bf16x8*)&Hb[(rgrp * 32 + 16 + (lane & 15)) * HSTR + ks * 32 + (lane >> 4) * 8];
#pragma unroll
    for (int c = 0; c < 4; ++c) {
      int ct = ch * 4 + c;
      bf16x8 bh = *(const bf16x8*)&Bhs[(ct * 64 + lane) * 8];
      bf16x8 bl = *(const bf16x8*)&Bls[(ct * 64 + lane) * 8];
      acc[0][c] = __builtin_amdgcn_mfma_f32_16x16x32_bf16(a0, bh, acc[0][c], 0, 0, 0);
      acc[0][c] = __builtin_amdgcn_mfma_f32_16x16x32_bf16(a0, bl, acc[0][c], 0, 0, 0);
      acc[1][c] = __builtin_amdgcn_mfma_f32_16x16x32_bf16(a1, bh, acc[1][c], 0, 0, 0);
      acc[1][c] = __builtin_amdgcn_mfma_f32_16x16x32_bf16(a1, bl, acc[1][c], 0, 0, 0);
    }
    __syncthreads();
  }

  // ---- epilogue: X = acc + b2 (no relu) ----
#pragma unroll
  for (int c = 0; c < 4; ++c) {
    int colg = (ch * 4 + c) * 16 + coln;
    float bv = b2[colg];
#pragma unroll
    for (int r = 0; r < 2; ++r) {
#pragma unroll
      for (int reg = 0; reg < 4; ++reg) {
        int row = m0 + rgrp * 32 + r * 16 + rown + reg;
        if (row < M) X[(size_t)row * DH + colg] = acc[r][c][reg] + bv;
      }
    }
  }
}

// ---------------------------------------------------------------------------
// CSR build: degree histogram -> exclusive scan (3 kernels) -> cursor fill.
// ---------------------------------------------------------------------------
__global__ __launch_bounds__(256) void count_deg(const int* __restrict__ eidx,
                                                 int* __restrict__ cnt) {
  int e = blockIdx.x * 256 + threadIdx.x;
  if (e < N_EDGES) atomicAdd(&cnt[eidx[N_EDGES + e]], 1);
}

__global__ __launch_bounds__(256) void scan_block(const int* __restrict__ cnt,
                                                  int* __restrict__ rs,
                                                  int* __restrict__ partials) {
  int t = threadIdx.x;
  int i = blockIdx.x * 256 + t;
  int v = (i < N_NODES) ? cnt[i] : 0;
  __shared__ int s[256];
  s[t] = v;
  __syncthreads();
#pragma unroll
  for (int off = 1; off < 256; off <<= 1) {
    int add = (t >= off) ? s[t - off] : 0;
    __syncthreads();
    s[t] += add;
    __syncthreads();
  }
  if (i < N_NODES) rs[i] = s[t] - v;
  if (t == 255) partials[blockIdx.x] = s[255];
}

__global__ __launch_bounds__(256) void scan_partials(int* __restrict__ partials) {
  int t = threadIdx.x;
  int v = (t < SCAN_BLOCKS) ? partials[t] : 0;
  __shared__ int s[256];
  s[t] = v;
  __syncthreads();
#pragma unroll
  for (int off = 1; off < 256; off <<= 1) {
    int add = (t >= off) ? s[t - off] : 0;
    __syncthreads();
    s[t] += add;
    __syncthreads();
  }
  if (t < SCAN_BLOCKS) partials[t] = s[t] - v;
}

__global__ __launch_bounds__(256) void add_offsets(int* __restrict__ rs,
                                                   const int* __restrict__ partials) {
  int i = blockIdx.x * 256 + threadIdx.x;
  if (i < N_NODES) rs[i] += partials[blockIdx.x];
  if (i == 0) rs[N_NODES] = N_EDGES;
}

__global__ __launch_bounds__(256) void fill_csr(const int* __restrict__ eidx,
                                                const int* __restrict__ rs,
                                                int* __restrict__ cursor,
                                                int* __restrict__ esrc) {
  int e = blockIdx.x * 256 + threadIdx.x;
  if (e >= N_EDGES) return;
  int d = eidx[N_EDGES + e];
  int p = atomicAdd(&cursor[d], 1);
  esrc[rs[d] + p] = eidx[e];
}

// ---------------------------------------------------------------------------
// Aggregation gather (bf16 neighbors): yb[i] = bf16(x[i] + sum_j xb[src_j]).
// Wave per node; lane handles dims (2*lane, 2*lane+1) via one uint load/edge.
// ---------------------------------------------------------------------------
__global__ __launch_bounds__(256) void gin_aggregate_bf16(
    const unsigned short* __restrict__ xb, const float* __restrict__ x,
    const int* __restrict__ rs, const int* __restrict__ esrc,
    unsigned* __restrict__ yb) {
  int node = blockIdx.x * 4 + (threadIdx.x >> 6);
  int lane = threadIdx.x & 63;
  if (node >= N_NODES) return;
  float2 acc = ((const float2*)x)[(size_t)node * 64 + lane];
  const unsigned* xb2 = (const unsigned*)xb;  // 2 bf16 per uint
  int beg = rs[node];
  int end = rs[node + 1];
  int j = beg;
  for (; j + 4 <= end; j += 4) {
    int s0 = esrc[j + 0];
    int s1 = esrc[j + 1];
    int s2 = esrc[j + 2];
    int s3 = esrc[j + 3];
    unsigned v0 = xb2[(size_t)s0 * 64 + lane];
    unsigned v1 = xb2[(size_t)s1 * 64 + lane];
    unsigned v2 = xb2[(size_t)s2 * 64 + lane];
    unsigned v3 = xb2[(size_t)s3 * 64 + lane];
    acc.x += (__uint_as_float(v0 << 16) + __uint_as_float(v1 << 16)) +
             (__uint_as_float(v2 << 16) + __uint_as_float(v3 << 16));
    acc.y += (__uint_as_float(v0 & 0xFFFF0000u) + __uint_as_float(v1 & 0xFFFF0000u)) +
             (__uint_as_float(v2 & 0xFFFF0000u) + __uint_as_float(v3 & 0xFFFF0000u));
  }
  for (; j < end; ++j) {
    unsigned v = xb2[(size_t)esrc[j] * 64 + lane];
    acc.x += __uint_as_float(v << 16);
    acc.y += __uint_as_float(v & 0xFFFF0000u);
  }
  yb[(size_t)node * 64 + lane] =
      (unsigned)f2bf(acc.x) | ((unsigned)f2bf(acc.y) << 16);
}

// ---------------------------------------------------------------------------
// Tail: z[i] = dot(x[i,:], tail_W) + tail_b, plus BN batch-stat partials.
// ---------------------------------------------------------------------------
__global__ __launch_bounds__(256) void tail_bn1(const float* __restrict__ x,
                                                const float* __restrict__ tw,
                                                const float* __restrict__ tb,
                                                float* __restrict__ z,
                                                float* __restrict__ red) {
  const int lane = threadIdx.x & 31;
  const int grp = threadIdx.x >> 5;
  float4 w = *(const float4*)(tw + lane * 4);
  float accS = 0.f, accQ = 0.f;
  for (int node = blockIdx.x * 8 + grp; node < N_NODES; node += gridDim.x * 8) {
    float4 v = *(const float4*)(x + (size_t)node * DH + lane * 4);
    float p = v.x * w.x + v.y * w.y + v.z * w.z + v.w * w.w;
#pragma unroll
    for (int m = 16; m; m >>= 1) p += __shfl_xor(p, m, 32);
    if (lane == 0) {
      float zv = p + tb[0];
      z[node] = zv;
      accS += zv;
      accQ += zv * zv;
    }
  }
  __shared__ float sS[256];
  __shared__ float sQ[256];
  sS[threadIdx.x] = accS;
  sQ[threadIdx.x] = accQ;
  __syncthreads();
  for (int s = 128; s; s >>= 1) {
    if (threadIdx.x < s) {
      sS[threadIdx.x] += sS[threadIdx.x + s];
      sQ[threadIdx.x] += sQ[threadIdx.x + s];
    }
    __syncthreads();
  }
  if (threadIdx.x == 0) {
    atomicAdd(&red[0], sS[0]);
    atomicAdd(&red[1], sQ[0]);
  }
}

__global__ __launch_bounds__(256) void bn2(const float* __restrict__ z,
                                           const float* __restrict__ red,
                                           const float* __restrict__ gamma,
                                           const float* __restrict__ beta,
                                           float* __restrict__ out) {
  int i = blockIdx.x * 256 + threadIdx.x;
  if (i >= N_NODES) return;
  float mu = red[0] * (1.0f / N_NODES);
  float var = red[1] * (1.0f / N_NODES) - mu * mu;
  out[i] = (z[i] - mu) * rsqrtf(var + BN_EPS) * gamma[0] + beta[0];
}

// ---------------------------------------------------------------------------
extern "C" void kernel_launch(void* const* d_in, const int* in_sizes, int n_in,
                              void* d_out, int out_size, void* d_ws, size_t ws_size,
                              hipStream_t stream) {
  const float* feature = (const float*)d_in[0];
  const int* eidx = (const int*)d_in[1];
  const float* head_W = (const float*)d_in[2];
  const float* head_b = (const float*)d_in[3];
  const float* gin_W1 = (const float*)d_in[4];
  const float* gin_b1 = (const float*)d_in[5];
  const float* lin_W1 = (const float*)d_in[6];
  const float* lin_b1 = (const float*)d_in[7];
  const float* gin_W2 = (const float*)d_in[8];
  const float* gin_b2 = (const float*)d_in[9];
  const float* lin_W2 = (const float*)d_in[10];
  const float* lin_b2 = (const float*)d_in[11];
  const float* tail_W = (const float*)d_in[12];
  const float* tail_b = (const float*)d_in[13];
  const float* bn_gamma = (const float*)d_in[14];
  const float* bn_beta = (const float*)d_in[15];

  float* X = (float*)d_ws;                       // N x 128 fp32
  float* z = X + (size_t)N_NODES * DH;           // N
  float* red = z + N_NODES;                      // 2 floats
  int* row_start = (int*)(red + 2);              // N+1
  int* cnt = row_start + (N_NODES + 1);          // N
  int* partials = cnt + N_NODES;                 // 256
  int* esrc = partials + 256;                    // E
  unsigned short* wp =
      (unsigned short*)(((uintptr_t)(esrc + N_EDGES) + 15) & ~(uintptr_t)15);
  unsigned short* hH = wp;            // head hi: 512*128
  unsigned short* hL = hH + 65536;    // head lo
  unsigned short* g1H = hL + 65536;   // 128*128 each below
  unsigned short* g1L = g1H + 16384;
  unsigned short* l1H = g1L + 16384;
  unsigned short* l1L = l1H + 16384;
  unsigned short* g2H = l1L + 16384;
  unsigned short* g2L = g2H + 16384;
  unsigned short* l2H = g2L + 16384;
  unsigned short* l2L = l2H + 16384;
  unsigned short* xb = l2L + 16384;              // bf16 mirror, N x 128
  unsigned short* yb = xb + (size_t)N_NODES * DH;  // agg out bf16, N x 128

  const int gemm_grid = (N_NODES + 63) / 64;     // 782
  const int edge_grid = (N_EDGES + 255) / 256;
  const int agg_grid = (N_NODES + 3) / 4;
  const int cvt_grid = (N_NODES * DH / 4 + 255) / 256;

  // ---- weight pre-split: one fused launch ----
  convert_W5<<<512, 256, 0, stream>>>(head_W, gin_W1, lin_W1, gin_W2, lin_W2,
                                      hH, hL, g1H, g1L, l1H, l1L, g2H, g2L,
                                      l2H, l2L);

  // ---- CSR build (once; reused by both GIN layers) ----
  hipMemsetAsync(cnt, 0, N_NODES * sizeof(int), stream);
  hipMemsetAsync(red, 0, 2 * sizeof(float), stream);
  count_deg<<<edge_grid, 256, 0, stream>>>(eidx, cnt);
  scan_block<<<SCAN_BLOCKS, 256, 0, stream>>>(cnt, row_start, partials);
  scan_partials<<<1, 256, 0, stream>>>(partials);
  add_offsets<<<SCAN_BLOCKS, 256, 0, stream>>>(row_start, partials);
  hipMemsetAsync(cnt, 0, N_NODES * sizeof(int), stream);
  fill_csr<<<edge_grid, 256, 0, stream>>>(eidx, row_start, cnt, esrc);

  // ---- head: X = relu(feature @ head_W + head_b) ----
  gemm_head<<<gemm_grid, 256, 0, stream>>>(feature, hH, hL, head_b, X, N_NODES);

  // ---- layer 1 (fused GIN MLP pair) ----
  to_bf16<<<cvt_grid, 256, 0, stream>>>(X, xb);
  gin_aggregate_bf16<<<agg_grid, 256, 0, stream>>>(xb, X, row_start, esrc,
                                                   (unsigned*)yb);
  gemm_gin<<<gemm_grid, 256, 0, stream>>>(yb, g1H, g1L, gin_b1, l1H, l1L,
                                          lin_b1, X, N_NODES);

  // ---- layer 2 ----
  to_bf16<<<cvt_grid, 256, 0, stream>>>(X, xb);
  gin_aggregate_bf16<<<agg_grid, 256, 0, stream>>>(xb, X, row_start, esrc,
                                                   (unsigned*)yb);
  gemm_gin<<<gemm_grid, 256, 0, stream>>>(yb, g2H, g2L, gin_b2, l2H, l2L,
                                          lin_b2, X, N_NODES);

  // ---- tail + batchnorm ----
  tail_bn1<<<256, 256, 0, stream>>>(X, tail_W, tail_b, z, red);
  bn2<<<(N_NODES + 255) / 256, 256, 0, stream>>>(z, red, bn_gamma, bn_beta, (float*)d_out);
}